// Round 3
// baseline (718.704 us; speedup 1.0000x reference)
//
#include <hip/hip_runtime.h>

// GraphLinear: out[b,n,o] = sum_m g[n,m] * (sum_i input[b,m,i]*W[type[m],o,i]) + bias[o]
// B=16384, N=128, DIN=DOUT=64, T=16.
// prep: bf16-convert weight/g; build groups of 8 same-type m's.
// main: BT=2 b-rows/block, 256 threads (4 waves), 32 KiB LDS -> 5 blocks/CU target.
//   Stage 1: grouped MFMA (8 m x 2 b share one W[t]) -> h in LDS (bf16, XOR-swizzled m).
//   Stage 2: wave = (b, n-half); A=h^T B=g^T so epilogue stores are dwordx4.

#define NN   128
#define DI   64
#define DOUT 64
#define BT   2
#define TT   16
#define MAXG 32

typedef __attribute__((ext_vector_type(4))) float f32x4;
typedef __attribute__((ext_vector_type(8))) short bf16x8;

__device__ __forceinline__ short f2bf(float f) {
    unsigned u = __builtin_bit_cast(unsigned, f);
    u += 0x7FFFu + ((u >> 16) & 1u);   // round-to-nearest-even
    return (short)(u >> 16);
}

__device__ __forceinline__ bf16x8 load8cvt(const float* __restrict__ p) {
    const f32x4 a = *(const f32x4*)p;
    const f32x4 b = *(const f32x4*)(p + 4);
    bf16x8 r;
    r[0] = f2bf(a[0]); r[1] = f2bf(a[1]); r[2] = f2bf(a[2]); r[3] = f2bf(a[3]);
    r[4] = f2bf(b[0]); r[5] = f2bf(b[1]); r[6] = f2bf(b[2]); r[7] = f2bf(b[3]);
    return r;
}

// Device-global scratch (rewritten every launch by prep_kernel; deterministic).
__device__ short d_wb[TT * DOUT * DI];          // bf16 weight [t][o][i], 128 KB
__device__ short d_gb[NN * NN];                 // bf16 g [n][m], 32 KB
__device__ int   d_groups[1 + MAXG + MAXG * 8]; // [G, type[32], gm[32][8] (-1 = pad)]

__global__ void prep_kernel(const float* __restrict__ weight,
                            const float* __restrict__ g,
                            const int*   __restrict__ ntype) {
    const int tid    = blockIdx.x * blockDim.x + threadIdx.x;
    const int stride = gridDim.x * blockDim.x;
    for (int i = tid; i < TT * DOUT * DI; i += stride) d_wb[i] = f2bf(weight[i]);
    for (int i = tid; i < NN * NN; i += stride)        d_gb[i] = f2bf(g[i]);
    if (tid == 0) {
        int G = 0;
        for (int t = 0; t < TT; ++t) {
            int mbuf[8]; int cur = 0;
            for (int m = 0; m < NN; ++m) {
                if (ntype[m] == t) {
                    mbuf[cur++] = m;
                    if (cur == 8) {
                        d_groups[1 + G] = t;
                        for (int k = 0; k < 8; ++k) d_groups[1 + MAXG + G*8 + k] = mbuf[k];
                        ++G; cur = 0;
                    }
                }
            }
            if (cur > 0) {
                d_groups[1 + G] = t;
                for (int k = 0; k < 8; ++k)
                    d_groups[1 + MAXG + G*8 + k] = (k < cur) ? mbuf[k] : -1;
                ++G;
            }
        }
        d_groups[0] = G;   // 16 <= G <= 30
    }
}

__global__ __launch_bounds__(256, 5)
void graph_linear_main(const float* __restrict__ input,   // [B,128,64] f32
                       const float* __restrict__ bias,    // [64] f32
                       float* __restrict__ out)           // [B,128,64] f32
{
    // h: [b=2][o=64][m=128] bf16 = 32 KiB; m XOR-swizzled by ((o&7)<<3).
    __shared__ short hbuf[BT * DOUT * NN];

    const int tid  = threadIdx.x;
    const int lane = tid & 63;
    const int wave = tid >> 6;        // 0..3
    const int lo   = lane & 15;
    const int hi   = lane >> 4;       // 0..3
    const int b0   = blockIdx.x * BT;

    // ---------------- stage 1: grouped MFMA, A rows r = mi*2 + bi ----------------
    const int G  = d_groups[0];
    const int Gq = (G + 3) >> 2;
    const int g_beg = wave * Gq;
    const int g_end = (g_beg + Gq < G) ? (g_beg + Gq) : G;

    for (int gi = g_beg; gi < g_end; ++gi) {
        const int t  = d_groups[1 + gi];
        const int* gm = &d_groups[1 + MAXG + gi * 8];
        const int mA  = gm[lo >> 1];                       // A-row: mi=lo>>1, bi=lo&1
        const int mAe = (mA < 0) ? 0 : mA;
        const float* irow = input + ((size_t)(b0 + (lo & 1)) * NN + mAe) * DI;
        const bf16x8 a0 = load8cvt(irow + hi * 8);         // k = 0..31
        const bf16x8 a1 = load8cvt(irow + 32 + hi * 8);    // k = 32..63

        const short* wrow = d_wb + t * (DOUT * DI);
        f32x4 hacc[4];
#pragma unroll
        for (int ot = 0; ot < 4; ++ot) hacc[ot] = 0.0f;
#pragma unroll
        for (int ot = 0; ot < 4; ++ot) {
            const int o = ot * 16 + lo;                    // B-frag col
            const bf16x8 w0 = *(const bf16x8*)(wrow + o * DI + hi * 8);
            hacc[ot] = __builtin_amdgcn_mfma_f32_16x16x32_bf16(a0, w0, hacc[ot], 0, 0, 0);
            const bf16x8 w1 = *(const bf16x8*)(wrow + o * DI + 32 + hi * 8);
            hacc[ot] = __builtin_amdgcn_mfma_f32_16x16x32_bf16(a1, w1, hacc[ot], 0, 0, 0);
        }
        // D rows r = hi*4+j: j=0 ->(mS0,b0) j=1 ->(mS0,b1) j=2 ->(mS1,b0) j=3 ->(mS1,b1)
        const int mS0 = gm[hi * 2];
        const int mS1 = gm[hi * 2 + 1];
#pragma unroll
        for (int ot = 0; ot < 4; ++ot) {
            const int o   = ot * 16 + lo;
            const int swz = (o & 7) << 3;
            if (mS0 >= 0) {
                hbuf[(0 * DOUT + o) * NN + (mS0 ^ swz)] = f2bf(hacc[ot][0]);
                hbuf[(1 * DOUT + o) * NN + (mS0 ^ swz)] = f2bf(hacc[ot][1]);
            }
            if (mS1 >= 0) {
                hbuf[(0 * DOUT + o) * NN + (mS1 ^ swz)] = f2bf(hacc[ot][2]);
                hbuf[(1 * DOUT + o) * NN + (mS1 ^ swz)] = f2bf(hacc[ot][3]);
            }
        }
    }
    __syncthreads();

    // ---------------- stage 2: wave -> (bi = w&1, n-half = w>>1) ----------------
    const int bi = wave & 1;
    const int nh = wave >> 1;

    bf16x8 hfr[4][4];   // A = h^T: row=o (lane lo), k=m
#pragma unroll
    for (int c = 0; c < 4; ++c)
#pragma unroll
        for (int ot = 0; ot < 4; ++ot) {
            const int o   = ot * 16 + lo;
            const int pos = (c * 32 + hi * 8) ^ ((o & 7) << 3);
            hfr[c][ot] = *(const bf16x8*)&hbuf[(bi * DOUT + o) * NN + pos];
        }
    f32x4 bvv[4];
#pragma unroll
    for (int ot = 0; ot < 4; ++ot)
        bvv[ot] = *(const f32x4*)(bias + ot * 16 + hi * 4);

    const size_t outb = (size_t)(b0 + bi) * NN;
#pragma unroll
    for (int nt = 0; nt < 4; ++nt) {
        const int n = nh * 64 + nt * 16 + lo;              // B-frag col = n
        bf16x8 gfr[4];
#pragma unroll
        for (int c = 0; c < 4; ++c)
            gfr[c] = *(const bf16x8*)(d_gb + n * NN + c * 32 + hi * 8);
        f32x4 acc[4];
#pragma unroll
        for (int ot = 0; ot < 4; ++ot) acc[ot] = bvv[ot];  // bias pre-added
#pragma unroll
        for (int c = 0; c < 4; ++c)
#pragma unroll
            for (int ot = 0; ot < 4; ++ot)
                acc[ot] = __builtin_amdgcn_mfma_f32_16x16x32_bf16(hfr[c][ot], gfr[c], acc[ot], 0, 0, 0);
        // D: col=lo -> n, row=hi*4+j -> o = ot*16+hi*4+j  => dwordx4 store
#pragma unroll
        for (int ot = 0; ot < 4; ++ot)
            *(f32x4*)&out[(outb + n) * DOUT + ot * 16 + hi * 4] = acc[ot];
    }
}

extern "C" void kernel_launch(void* const* d_in, const int* in_sizes, int n_in,
                              void* d_out, int out_size, void* d_ws, size_t ws_size,
                              hipStream_t stream) {
    const float* input  = (const float*)d_in[0];
    const float* g      = (const float*)d_in[1];
    const float* weight = (const float*)d_in[2];
    const float* bias   = (const float*)d_in[3];
    const int*   ntype  = (const int*)d_in[4];
    float* out = (float*)d_out;

    const int B = in_sizes[0] / (NN * DI);   // 16384

    hipLaunchKernelGGL(prep_kernel, dim3(32), dim3(256), 0, stream, weight, g, ntype);
    hipLaunchKernelGGL(graph_linear_main, dim3(B / BT), dim3(256), 0, stream,
                       input, bias, out);
}

// Round 4
// 552.443 us; speedup vs baseline: 1.3010x; 1.3010x over previous
//
#include <hip/hip_runtime.h>

// GraphLinear: out[b,n,o] = sum_m g[n,m] * (sum_i input[b,m,i]*W[type[m],o,i]) + bias[o]
// B=16384, N=128, DIN=DOUT=64, T=16.
// prep: bf16-convert weight/g; build groups of 8 same-type m's.
// main: BT=2 b-rows/block, 256 threads (4 waves), 32 KiB LDS.
//   Stage 1: grouped MFMA (8 m x 2 b share one W[t]) -> h in LDS (bf16, XOR-swizzled m).
//   Stage 2: fully-streamed (low VGPR): per n-tile, per k-chunk, load g/h frags and MFMA.
//            A=h^T B=g^T so epilogue stores are contiguous dwordx4 (nontemporal).
// __launch_bounds__(256,4): budget 128 VGPR (no spill); actual residency is
// min(LDS 5 blocks/CU, 512/VGPR) -> 5 blocks/CU if VGPR <= 102.

#define NN   128
#define DI   64
#define DOUT 64
#define BT   2
#define TT   16
#define MAXG 32

typedef __attribute__((ext_vector_type(4))) float f32x4;
typedef __attribute__((ext_vector_type(8))) short bf16x8;

__device__ __forceinline__ short f2bf(float f) {
    unsigned u = __builtin_bit_cast(unsigned, f);
    u += 0x7FFFu + ((u >> 16) & 1u);   // round-to-nearest-even
    return (short)(u >> 16);
}

__device__ __forceinline__ bf16x8 load8cvt(const float* __restrict__ p) {
    const f32x4 a = *(const f32x4*)p;
    const f32x4 b = *(const f32x4*)(p + 4);
    bf16x8 r;
    r[0] = f2bf(a[0]); r[1] = f2bf(a[1]); r[2] = f2bf(a[2]); r[3] = f2bf(a[3]);
    r[4] = f2bf(b[0]); r[5] = f2bf(b[1]); r[6] = f2bf(b[2]); r[7] = f2bf(b[3]);
    return r;
}

// Device-global scratch (rewritten every launch by prep_kernel; deterministic).
__device__ short d_wb[TT * DOUT * DI];          // bf16 weight [t][o][i], 128 KB
__device__ short d_gb[NN * NN];                 // bf16 g [n][m], 32 KB
__device__ int   d_groups[1 + MAXG + MAXG * 8]; // [G, type[32], gm[32][8] (-1 = pad)]

__global__ void prep_kernel(const float* __restrict__ weight,
                            const float* __restrict__ g,
                            const int*   __restrict__ ntype) {
    const int tid    = blockIdx.x * blockDim.x + threadIdx.x;
    const int stride = gridDim.x * blockDim.x;
    for (int i = tid; i < TT * DOUT * DI; i += stride) d_wb[i] = f2bf(weight[i]);
    for (int i = tid; i < NN * NN; i += stride)        d_gb[i] = f2bf(g[i]);
    if (tid == 0) {
        int G = 0;
        for (int t = 0; t < TT; ++t) {
            int mbuf[8]; int cur = 0;
            for (int m = 0; m < NN; ++m) {
                if (ntype[m] == t) {
                    mbuf[cur++] = m;
                    if (cur == 8) {
                        d_groups[1 + G] = t;
                        for (int k = 0; k < 8; ++k) d_groups[1 + MAXG + G*8 + k] = mbuf[k];
                        ++G; cur = 0;
                    }
                }
            }
            if (cur > 0) {
                d_groups[1 + G] = t;
                for (int k = 0; k < 8; ++k)
                    d_groups[1 + MAXG + G*8 + k] = (k < cur) ? mbuf[k] : -1;
                ++G;
            }
        }
        d_groups[0] = G;   // 16 <= G <= 30
    }
}

__global__ __launch_bounds__(256, 4)
void graph_linear_main(const float* __restrict__ input,   // [B,128,64] f32
                       const float* __restrict__ bias,    // [64] f32
                       float* __restrict__ out)           // [B,128,64] f32
{
    // h: [b=2][o=64][m=128] bf16 = 32 KiB; m XOR-swizzled by ((o&7)<<3).
    __shared__ short hbuf[BT * DOUT * NN];

    const int tid  = threadIdx.x;
    const int lane = tid & 63;
    const int wave = tid >> 6;        // 0..3
    const int lo   = lane & 15;
    const int hi   = lane >> 4;       // 0..3
    const int b0   = blockIdx.x * BT;

    // ---------------- stage 1: grouped MFMA, A rows r = mi*2 + bi ----------------
    const int G  = d_groups[0];
    const int Gq = (G + 3) >> 2;
    const int g_beg = wave * Gq;
    const int g_end = (g_beg + Gq < G) ? (g_beg + Gq) : G;

    for (int gi = g_beg; gi < g_end; ++gi) {
        const int t  = d_groups[1 + gi];
        const int* gm = &d_groups[1 + MAXG + gi * 8];
        const int mA  = gm[lo >> 1];                       // A-row: mi=lo>>1, bi=lo&1
        const int mAe = (mA < 0) ? 0 : mA;
        const float* irow = input + ((size_t)(b0 + (lo & 1)) * NN + mAe) * DI;
        const bf16x8 a0 = load8cvt(irow + hi * 8);         // k = 0..31
        const bf16x8 a1 = load8cvt(irow + 32 + hi * 8);    // k = 32..63

        const short* wrow = d_wb + t * (DOUT * DI);
        f32x4 hacc[4];
#pragma unroll
        for (int ot = 0; ot < 4; ++ot) hacc[ot] = 0.0f;
#pragma unroll
        for (int ot = 0; ot < 4; ++ot) {
            const int o = ot * 16 + lo;                    // B-frag col
            const bf16x8 w0 = *(const bf16x8*)(wrow + o * DI + hi * 8);
            hacc[ot] = __builtin_amdgcn_mfma_f32_16x16x32_bf16(a0, w0, hacc[ot], 0, 0, 0);
            const bf16x8 w1 = *(const bf16x8*)(wrow + o * DI + 32 + hi * 8);
            hacc[ot] = __builtin_amdgcn_mfma_f32_16x16x32_bf16(a1, w1, hacc[ot], 0, 0, 0);
        }
        // D rows r = hi*4+j: j=0 ->(mS0,b0) j=1 ->(mS0,b1) j=2 ->(mS1,b0) j=3 ->(mS1,b1)
        const int mS0 = gm[hi * 2];
        const int mS1 = gm[hi * 2 + 1];
#pragma unroll
        for (int ot = 0; ot < 4; ++ot) {
            const int o   = ot * 16 + lo;
            const int swz = (o & 7) << 3;
            if (mS0 >= 0) {
                hbuf[(0 * DOUT + o) * NN + (mS0 ^ swz)] = f2bf(hacc[ot][0]);
                hbuf[(1 * DOUT + o) * NN + (mS0 ^ swz)] = f2bf(hacc[ot][1]);
            }
            if (mS1 >= 0) {
                hbuf[(0 * DOUT + o) * NN + (mS1 ^ swz)] = f2bf(hacc[ot][2]);
                hbuf[(1 * DOUT + o) * NN + (mS1 ^ swz)] = f2bf(hacc[ot][3]);
            }
        }
    }
    __syncthreads();

    // ---------------- stage 2: wave -> (bi = w&1, n-half = w>>1), streamed ----------------
    const int bi = wave & 1;
    const int nh = wave >> 1;

    f32x4 bvv[4];
#pragma unroll
    for (int ot = 0; ot < 4; ++ot)
        bvv[ot] = *(const f32x4*)(bias + ot * 16 + hi * 4);

    const size_t outb = (size_t)(b0 + bi) * NN;
    const short* hrow = hbuf + bi * (DOUT * NN);

#pragma unroll
    for (int nt = 0; nt < 4; ++nt) {
        const int n = nh * 64 + nt * 16 + lo;              // B-frag col = n
        f32x4 acc[4];
#pragma unroll
        for (int ot = 0; ot < 4; ++ot) acc[ot] = bvv[ot];  // bias pre-added
#pragma unroll
        for (int c = 0; c < 4; ++c) {
            const bf16x8 gfr = *(const bf16x8*)(d_gb + n * NN + c * 32 + hi * 8);
#pragma unroll
            for (int ot = 0; ot < 4; ++ot) {
                const int o   = ot * 16 + lo;              // A-frag row = o
                const int pos = (c * 32 + hi * 8) ^ ((o & 7) << 3);
                const bf16x8 hfr = *(const bf16x8*)&hrow[o * NN + pos];
                acc[ot] = __builtin_amdgcn_mfma_f32_16x16x32_bf16(hfr, gfr, acc[ot], 0, 0, 0);
            }
        }
        // D: col=lo -> n, row=hi*4+j -> o = ot*16+hi*4+j  => contiguous dwordx4 store
#pragma unroll
        for (int ot = 0; ot < 4; ++ot) {
            f32x4* dst = (f32x4*)&out[(outb + n) * DOUT + ot * 16 + hi * 4];
            __builtin_nontemporal_store(acc[ot], dst);
        }
    }
}

extern "C" void kernel_launch(void* const* d_in, const int* in_sizes, int n_in,
                              void* d_out, int out_size, void* d_ws, size_t ws_size,
                              hipStream_t stream) {
    const float* input  = (const float*)d_in[0];
    const float* g      = (const float*)d_in[1];
    const float* weight = (const float*)d_in[2];
    const float* bias   = (const float*)d_in[3];
    const int*   ntype  = (const int*)d_in[4];
    float* out = (float*)d_out;

    const int B = in_sizes[0] / (NN * DI);   // 16384

    hipLaunchKernelGGL(prep_kernel, dim3(32), dim3(256), 0, stream, weight, g, ntype);
    hipLaunchKernelGGL(graph_linear_main, dim3(B / BT), dim3(256), 0, stream,
                       input, bias, out);
}

// Round 5
// 447.960 us; speedup vs baseline: 1.6044x; 1.2332x over previous
//
#include <hip/hip_runtime.h>

// GraphLinear: out[b,n,o] = sum_m g[n,m] * (sum_i input[b,m,i]*W[type[m],o,i]) + bias[o]
// B=16384, N=128, DIN=DOUT=64, T=16.
// prep: bf16-convert weight/g; pack groups of 4 same-type m's into 2 ints each.
// main: BT=4 b-rows/block, 512 threads (8 waves), 64 KiB LDS, 2 blocks/CU.
//   Stage 1: grouped MFMA (4 m x 4 b share one W[t]); scalar (s_load) metadata;
//            explicit next-group input prefetch to hide HBM latency.
//   Stage 2: wave=(b, n-half); hoisted h-fragments (64 VGPR); A=h^T B=g^T so
//            epilogue stores are contiguous dwordx4 (plain stores - NT hurt WRITE_SIZE).

#define NN    128
#define DI    64
#define DOUT  64
#define BT    4
#define TT    16
#define MAXG4 64

typedef __attribute__((ext_vector_type(4))) float f32x4;
typedef __attribute__((ext_vector_type(8))) short bf16x8;

__device__ __forceinline__ short f2bf(float f) {
    unsigned u = __builtin_bit_cast(unsigned, f);
    u += 0x7FFFu + ((u >> 16) & 1u);   // round-to-nearest-even
    return (short)(u >> 16);
}

__device__ __forceinline__ bf16x8 load8cvt(const float* __restrict__ p) {
    const f32x4 a = *(const f32x4*)p;
    const f32x4 b = *(const f32x4*)(p + 4);
    bf16x8 r;
    r[0] = f2bf(a[0]); r[1] = f2bf(a[1]); r[2] = f2bf(a[2]); r[3] = f2bf(a[3]);
    r[4] = f2bf(b[0]); r[5] = f2bf(b[1]); r[6] = f2bf(b[2]); r[7] = f2bf(b[3]);
    return r;
}

// Device-global scratch (rewritten every launch by prep_kernel; deterministic).
__device__ short d_wb[TT * DOUT * DI];   // bf16 weight [t][o][i], 128 KB
__device__ short d_gb[NN * NN];          // bf16 g [n][m], 32 KB
__device__ int   d_gp[MAXG4 * 2];        // packed groups: {m0|m1<<8|m2<<16|m3<<24, type}
__device__ int   d_gcount[1];            // padded group count (multiple of 8)

__global__ void prep_kernel(const float* __restrict__ weight,
                            const float* __restrict__ g,
                            const int*   __restrict__ ntype) {
    const int tid    = blockIdx.x * blockDim.x + threadIdx.x;
    const int stride = gridDim.x * blockDim.x;
    for (int i = tid; i < TT * DOUT * DI; i += stride) d_wb[i] = f2bf(weight[i]);
    for (int i = tid; i < NN * NN; i += stride)        d_gb[i] = f2bf(g[i]);
    if (tid == 0) {
        int G = 0;
        for (int t = 0; t < TT; ++t) {
            int mbuf[4]; int cur = 0;
            for (int m = 0; m < NN; ++m) {
                if (ntype[m] == t) {
                    mbuf[cur++] = m;
                    if (cur == 4) {
                        d_gp[G * 2]     = mbuf[0] | (mbuf[1] << 8) | (mbuf[2] << 16) | (mbuf[3] << 24);
                        d_gp[G * 2 + 1] = t;
                        ++G; cur = 0;
                    }
                }
            }
            if (cur > 0) {
                int pk = 0;
                for (int k = 0; k < 4; ++k) pk |= ((k < cur) ? mbuf[k] : 0xFF) << (8 * k);
                d_gp[G * 2] = pk; d_gp[G * 2 + 1] = t; ++G;
            }
        }
        while (G & 7) { d_gp[G * 2] = (int)0xFFFFFFFF; d_gp[G * 2 + 1] = 0; ++G; }
        d_gcount[0] = G;   // <= 48, multiple of 8
    }
}

__global__ __launch_bounds__(512, 4)
void graph_linear_main(const float* __restrict__ input,   // [B,128,64] f32
                       const float* __restrict__ bias,    // [64] f32
                       float* __restrict__ out)           // [B,128,64] f32
{
    // h: [b=4][o=64][m=128] bf16 = 64 KiB; m XOR-swizzled by ((o&7)<<3).
    __shared__ short hbuf[BT * DOUT * NN];

    const int tid  = threadIdx.x;
    const int lane = tid & 63;
    const int wave = tid >> 6;        // 0..7
    const int lo   = lane & 15;
    const int hi   = lane >> 4;       // 0..3
    const int b0   = blockIdx.x * BT;

    // ---------------- stage 1: grouped MFMA, A rows r = mi*4 + bi ----------------
    const int iters = d_gcount[0] >> 3;    // groups padded to multiple of 8
    const int sl    = lo >> 2;             // A-row m-slot
    const float* const inpb = input + (size_t)(b0 + (lo & 3)) * NN * DI;

    // preload iteration 0 (metadata via scalar loads, input via prefetch regs)
    int giu = __builtin_amdgcn_readfirstlane(wave) * 2;
    int pk  = d_gp[giu];
    int tt  = d_gp[giu + 1];
    {
        const int mA  = (pk >> (8 * sl)) & 0xFF;
        const int mAe = (mA == 0xFF) ? (pk & 0x7F) : mA;   // alias slot-0 row (L2 hit)
        const float* irow = inpb + mAe * DI;
        // fallthrough into first loop body via a0/a1
        // (loads issued here, consumed in it=0)
        // NOTE: kept symmetric with in-loop prefetch
        // a0: k=0..31, a1: k=32..63
        // (declared below)
    }
    const int mA0  = (pk >> (8 * sl)) & 0xFF;
    const int mAe0 = (mA0 == 0xFF) ? (pk & 0x7F) : mA0;
    bf16x8 a0 = load8cvt(inpb + mAe0 * DI + hi * 8);
    bf16x8 a1 = load8cvt(inpb + mAe0 * DI + 32 + hi * 8);

    for (int it = 0; it < iters; ++it) {
        const int    pk_c = pk;
        const int    t_c  = tt;
        const bf16x8 a0c  = a0;
        const bf16x8 a1c  = a1;

        // prefetch next group's metadata + input fragments
        if (it + 1 < iters) {
            giu = __builtin_amdgcn_readfirstlane((it + 1) * 8 + wave) * 2;
            pk  = d_gp[giu];
            tt  = d_gp[giu + 1];
            const int mA  = (pk >> (8 * sl)) & 0xFF;
            const int mAe = (mA == 0xFF) ? (pk & 0x7F) : mA;
            a0 = load8cvt(inpb + mAe * DI + hi * 8);
            a1 = load8cvt(inpb + mAe * DI + 32 + hi * 8);
        }

        // weights (L2-hot bf16) + MFMA on current group
        const short* wrow = d_wb + t_c * (DOUT * DI);
        f32x4 hacc[4];
#pragma unroll
        for (int ot = 0; ot < 4; ++ot) hacc[ot] = 0.0f;
#pragma unroll
        for (int ot = 0; ot < 4; ++ot) {
            const int o = ot * 16 + lo;                    // B-frag col
            const bf16x8 w0 = *(const bf16x8*)(wrow + o * DI + hi * 8);
            hacc[ot] = __builtin_amdgcn_mfma_f32_16x16x32_bf16(a0c, w0, hacc[ot], 0, 0, 0);
            const bf16x8 w1 = *(const bf16x8*)(wrow + o * DI + 32 + hi * 8);
            hacc[ot] = __builtin_amdgcn_mfma_f32_16x16x32_bf16(a1c, w1, hacc[ot], 0, 0, 0);
        }
        // D: col(o)=lane&15, row r=hi*4+j -> m-slot=hi, b=j
        const int mS = (pk_c >> (8 * hi)) & 0xFF;
        if (mS != 0xFF) {
#pragma unroll
            for (int ot = 0; ot < 4; ++ot) {
                const int o = ot * 16 + lo;
                const int p = mS ^ ((o & 7) << 3);
#pragma unroll
                for (int j = 0; j < 4; ++j)
                    hbuf[(j * DOUT + o) * NN + p] = f2bf(hacc[ot][j]);
            }
        }
    }
    __syncthreads();

    // ---------------- stage 2: wave -> (bi = w>>1, n-half = w&1) ----------------
    const int bi = wave >> 1;
    const int nh = wave & 1;
    const short* hrow = hbuf + bi * (DOUT * NN);

    bf16x8 hfr[4][4];   // [k-chunk][o-tile] = 64 VGPRs, reused across 4 n-tiles
#pragma unroll
    for (int c = 0; c < 4; ++c)
#pragma unroll
        for (int ot = 0; ot < 4; ++ot) {
            const int o   = ot * 16 + lo;
            const int pos = (c * 32 + hi * 8) ^ ((o & 7) << 3);
            hfr[c][ot] = *(const bf16x8*)&hrow[o * NN + pos];
        }

    const size_t outb = (size_t)(b0 + bi) * NN;
#pragma unroll
    for (int nt = 0; nt < 4; ++nt) {
        const int n = nh * 64 + nt * 16 + lo;              // B-frag col = n
        f32x4 acc[4];
#pragma unroll
        for (int ot = 0; ot < 4; ++ot)
            acc[ot] = *(const f32x4*)(bias + ot * 16 + hi * 4);   // bias pre-added
#pragma unroll
        for (int c = 0; c < 4; ++c) {
            const bf16x8 gfr = *(const bf16x8*)(d_gb + n * NN + c * 32 + hi * 8);
#pragma unroll
            for (int ot = 0; ot < 4; ++ot)
                acc[ot] = __builtin_amdgcn_mfma_f32_16x16x32_bf16(hfr[c][ot], gfr, acc[ot], 0, 0, 0);
        }
        // D: col=lo -> n, row=hi*4+j -> o = ot*16+hi*4+j  => contiguous dwordx4
#pragma unroll
        for (int ot = 0; ot < 4; ++ot)
            *(f32x4*)&out[(outb + n) * DOUT + ot * 16 + hi * 4] = acc[ot];
    }
}

extern "C" void kernel_launch(void* const* d_in, const int* in_sizes, int n_in,
                              void* d_out, int out_size, void* d_ws, size_t ws_size,
                              hipStream_t stream) {
    const float* input  = (const float*)d_in[0];
    const float* g      = (const float*)d_in[1];
    const float* weight = (const float*)d_in[2];
    const float* bias   = (const float*)d_in[3];
    const int*   ntype  = (const int*)d_in[4];
    float* out = (float*)d_out;

    const int B = in_sizes[0] / (NN * DI);   // 16384

    hipLaunchKernelGGL(prep_kernel, dim3(32), dim3(256), 0, stream, weight, g, ntype);
    hipLaunchKernelGGL(graph_linear_main, dim3(B / BT), dim3(512), 0, stream,
                       input, bias, out);
}